// Round 2
// baseline (277.934 us; speedup 1.0000x reference)
//
#include <hip/hip_runtime.h>
#include <cstdint>

namespace {
constexpr int B = 8, C = 3, H = 1024, W = 1024;
constexpr int HO = 256, WO = 256, K2 = 9;
constexpr int HP = H + 2, WP = W + 2;
constexpr int HW = H * W, HOWO = HO * WO;

// Output tile per block: 32 wide x 16 tall, 512 threads, ONE channel each.
// Channel-split -> 53.5 KB LDS/block -> 3 blocks/CU (24 waves) instead of
// the round-1 monolith's 160 KB -> 1 block/CU (8 waves, latency-bound).
constexpr int TW = 32, TH = 16;
constexpr int NTX = WO / TW;            // 8 tiles in x
constexpr int NTY = HO / TH;            // 16 tiles in y
constexpr int NT  = NTX * NTY;          // 128 tiles per image
constexpr int OF = 12;                  // halo px = 3 sigma of 4*N(0,1) offsets
constexpr int WINW = 4 * TW + 2 * OF;   // 152
constexpr int WINH = 4 * TH + 2 * OF;   // 88
constexpr int WPX = WINW * WINH;        // 13376 px -> 53504 B as f32

__device__ __forceinline__ int reflect_src(int p, int n) {
    // padded index p in [0, n+1] -> source index in [0, n-1] (numpy 'reflect')
    int s = p - 1;
    s = (s < 0) ? -s : s;
    s = (s >= n) ? (2 * n - 2 - s) : s;
    return s;
}

// One block = (image b, tile t, channel c). Stage the tile's reflect-padded
// sampling window for channel c into LDS (coalesced), then serve the 36
// divergent bilinear corner reads from the LDS pipe. Identical arithmetic to
// the verified round-1 kernel, just channel-split for 3x occupancy.
__global__ __launch_bounds__(512, 6) void ds_split(
    const float* __restrict__ img,
    const float* __restrict__ kern,
    const float* __restrict__ offh,
    const float* __restrict__ offv,
    const float* __restrict__ ou_p,
    float* __restrict__ out) {
    __shared__ float win[WPX];

    const int b    = blockIdx.x & 7;     // XCD swizzle: image b -> XCD b
    const int rest = blockIdx.x >> 3;    // 0..383 ; (t,c) adjacent -> coef L2 reuse
    const int c    = rest % 3;
    const int t    = rest / 3;           // 0..127
    const int tid  = threadIdx.x;
    const int w0   = (t & (NTX - 1)) * TW;
    const int h0   = (t >> 3) * TH;
    const int X0   = 4 * w0 - (OF - 1);  // window origin in padded coords
    const int Y0   = 4 * h0 - (OF - 1);

    const float* __restrict__ p = img + ((size_t)b * C + c) * (size_t)HW;

    // ---- stage window: padded coords [Y0,Y0+WINH) x [X0,X0+WINW) ----
    for (int i = tid; i < WPX; i += 512) {
        int yy = i / WINW;
        int xx = i - yy * WINW;
        int Yp = min(max(Y0 + yy, 0), HP - 1);  // OOR slots are never read
        int Xp = min(max(X0 + xx, 0), WP - 1);
        int sy = reflect_src(Yp, H);
        int sx = reflect_src(Xp, W);
        win[i] = p[(size_t)sy * W + sx];
    }
    __syncthreads();

    const int lw = tid & (TW - 1);
    const int lh = tid >> 5;
    const int h = h0 + lh, w = w0 + lw;
    const float ou = ou_p[0];
    const float cy = (h + 0.5f) * 4.0f - 0.5f;
    const float cx = (w + 0.5f) * 4.0f - 0.5f;
    const size_t pb = ((size_t)b * K2) * (size_t)HOWO + (size_t)h * WO + w;

    float acc = 0.f;

#pragma unroll
    for (int k = 0; k < K2; ++k) {
        size_t o = pb + (size_t)(k * HOWO);
        float kv = kern[o];
        float py = cy + (float)(k / 3) + offv[o] * ou;
        float px = cx + (float)(k % 3) + offh[o] * ou;

        float y0f = floorf(py), x0f = floorf(px);
        float bb = py - y0f;
        float aa = px - x0f;

        int y0 = min(max((int)y0f, 0), HP - 1);
        int x0 = min(max((int)x0f, 0), WP - 1);
        int y1 = min(y0 + 1, HP - 1);
        int x1 = min(x0 + 1, WP - 1);

        float v00, v01, v10, v11;
        bool inw = (y0 >= Y0) & (y1 <= Y0 + WINH - 1) &
                   (x0 >= X0) & (x1 <= X0 + WINW - 1);
        if (__builtin_expect(inw, 1)) {
            int i00 = (y0 - Y0) * WINW + (x0 - X0);
            int dx  = x1 - x0;               // 1, or 0 at a clamped edge
            int dyr = (y1 - y0) * WINW;
            v00 = win[i00];
            v01 = win[i00 + dx];
            v10 = win[i00 + dyr];
            v11 = win[i00 + dyr + dx];
        } else {
            // Rare: |offset| beyond the staged halo. Exact replay of the
            // verified global reflect path (bit-identical result).
            int sy0 = reflect_src(y0, H), sy1 = reflect_src(y1, H);
            int sx0 = reflect_src(x0, W), sx1 = reflect_src(x1, W);
            v00 = p[(size_t)sy0 * W + sx0];
            v01 = p[(size_t)sy0 * W + sx1];
            v10 = p[(size_t)sy1 * W + sx0];
            v11 = p[(size_t)sy1 * W + sx1];
        }

        float tx_ = v00 + aa * (v01 - v00);
        float tu_ = v10 + aa * (v11 - v10);
        acc += kv * (tx_ + bb * (tu_ - tx_));
    }

    out[((size_t)b * C + c) * (size_t)HOWO + (size_t)h * WO + w] = acc;
}
} // namespace

extern "C" void kernel_launch(void* const* d_in, const int* in_sizes, int n_in,
                              void* d_out, int out_size, void* d_ws, size_t ws_size,
                              hipStream_t stream) {
    const float* img  = (const float*)d_in[0];
    const float* kern = (const float*)d_in[1];
    const float* offh = (const float*)d_in[2];
    const float* offv = (const float*)d_in[3];
    const float* ou   = (const float*)d_in[4];
    float* out = (float*)d_out;

    hipLaunchKernelGGL(ds_split, dim3(B * NT * C), dim3(512), 0, stream,
                       img, kern, offh, offv, ou, out);
}

// Round 3
// 221.696 us; speedup vs baseline: 1.2537x; 1.2537x over previous
//
#include <hip/hip_runtime.h>
#include <cstdint>

namespace {
constexpr int B = 8, C = 3, H = 1024, W = 1024;
constexpr int HO = 256, WO = 256, K2 = 9;
constexpr int HP = H + 2, WP = W + 2;
constexpr int HW = H * W, HOWO = HO * WO;

// One block = one 32x16 output tile, ALL 3 channels (no redundant coord math).
constexpr int TW = 32, TH = 16;
constexpr int NTX = WO / TW;            // 8 tiles in x
constexpr int NTY = HO / TH;            // 16 tiles in y
constexpr int NT  = NTX * NTY;          // 128 tiles per image
constexpr int OF = 12;                  // halo px = 3 sigma of 4*N(0,1) offsets
constexpr int WINW = 4 * TW + 2 * OF;   // 152 (x-origin 4px-aligned: X0-1 = 4w0-12)
constexpr int WINH = 4 * TH + 2 * OF;   // 88
constexpr int WPX  = WINW * WINH;       // 13376 px
constexpr int CPR  = WINW / 4;          // 38 float4-chunks per window row
constexpr int CHPP = CPR * WINH;        // 3344 chunks per plane

// LDS: lA = float2[WPX+2] (c0,c1 interleaved), lB = float[WPX+1] (c2).
// +spares cover the unconditional [i+1] pair-reads in the gather.
constexpr size_t LA_BYTES  = (size_t)(WPX + 2) * 8;          // 107024 (16B-aligned)
constexpr size_t LDS_BYTES = LA_BYTES + (size_t)(WPX + 1) * 4; // 160532 <= 163840

__device__ __forceinline__ int reflect_src(int p, int n) {
    // padded index p in [0, n+1] -> source index in [0, n-1] (numpy 'reflect')
    int s = p - 1;
    s = (s < 0) ? -s : s;
    s = (s >= n) ? (2 * n - 2 - s) : s;
    return s;
}

__global__ __launch_bounds__(512) void ds_fused(
    const float* __restrict__ img,
    const float* __restrict__ kern,
    const float* __restrict__ offh,
    const float* __restrict__ offv,
    const float* __restrict__ ou_p,
    float* __restrict__ out) {
    extern __shared__ unsigned char smem[];
    float2* __restrict__ lA = (float2*)smem;
    float*  __restrict__ lB = (float*)(smem + LA_BYTES);

    const int b   = blockIdx.x & 7;      // XCD swizzle: image b -> XCD b
    const int t   = blockIdx.x >> 3;     // tile 0..127
    const int tid = threadIdx.x;
    const int w0  = (t & (NTX - 1)) * TW;
    const int h0  = (t >> 3) * TH;
    const int X0  = 4 * w0 - (OF - 1);   // window origin in padded coords
    const int Y0  = 4 * h0 - (OF - 1);

    const float* __restrict__ p0 = img + (size_t)b * (C * HW);
    const float* __restrict__ p1 = p0 + HW;
    const float* __restrict__ p2 = p1 + HW;

    // ---- coefficient prefetch: 27 independent loads issued BEFORE staging,
    // so their HBM/L3 latency hides under the staging phase. Static indices
    // (full unroll) keep these in registers, not scratch.
    const int lw = tid & (TW - 1);
    const int lh = tid >> 5;
    const int h = h0 + lh, w = w0 + lw;
    const int pb = (b * K2) * HOWO + h * WO + w;   // < 2^31, int math
    float kv[K2], vv[K2], hh[K2];
#pragma unroll
    for (int k = 0; k < K2; ++k) {
        kv[k] = kern[pb + k * HOWO];
        vv[k] = offv[pb + k * HOWO];
        hh[k] = offh[pb + k * HOWO];
    }
    const float ou = ou_p[0];

    // ---- stage lA: (c0,c1) interleaved, float4-vectorized ----
    // chunk i -> window px base 4*i (since (i/38)*152 + (i%38)*4 == 4*i).
    for (int i = tid; i < CHPP; i += 512) {
        int yy = i / CPR, xc = i - yy * CPR;
        int Yp = min(max(Y0 + yy, 0), HP - 1);
        int sy = reflect_src(Yp, H);
        int gx = X0 - 1 + 4 * xc;        // global x of chunk start (4-aligned)
        float4 a0, a1;
        if (gx >= 0 && gx <= W - 4) {    // interior: aligned 16B loads
            a0 = *(const float4*)(p0 + (size_t)sy * W + gx);
            a1 = *(const float4*)(p1 + (size_t)sy * W + gx);
        } else {                          // x-edge: exact scalar reflect
            float t0[4], t1[4];
#pragma unroll
            for (int j = 0; j < 4; ++j) {
                int Xp = min(max(X0 + 4 * xc + j, 0), WP - 1);
                int sx = reflect_src(Xp, W);
                t0[j] = p0[(size_t)sy * W + sx];
                t1[j] = p1[(size_t)sy * W + sx];
            }
            a0 = make_float4(t0[0], t0[1], t0[2], t0[3]);
            a1 = make_float4(t1[0], t1[1], t1[2], t1[3]);
        }
        float4* dst = (float4*)(lA + 4 * i);           // 32B-aligned
        dst[0] = make_float4(a0.x, a1.x, a0.y, a1.y);
        dst[1] = make_float4(a0.z, a1.z, a0.w, a1.w);
    }
    // ---- stage lB: c2 planar, float4-vectorized ----
    for (int i = tid; i < CHPP; i += 512) {
        int yy = i / CPR, xc = i - yy * CPR;
        int Yp = min(max(Y0 + yy, 0), HP - 1);
        int sy = reflect_src(Yp, H);
        int gx = X0 - 1 + 4 * xc;
        float4 a2;
        if (gx >= 0 && gx <= W - 4) {
            a2 = *(const float4*)(p2 + (size_t)sy * W + gx);
        } else {
            float t2[4];
#pragma unroll
            for (int j = 0; j < 4; ++j) {
                int Xp = min(max(X0 + 4 * xc + j, 0), WP - 1);
                int sx = reflect_src(Xp, W);
                t2[j] = p2[(size_t)sy * W + sx];
            }
            a2 = make_float4(t2[0], t2[1], t2[2], t2[3]);
        }
        *(float4*)(lB + 4 * i) = a2;                   // 16B-aligned
    }
    __syncthreads();

    const float cy = (h + 0.5f) * 4.0f - 0.5f;
    const float cx = (w + 0.5f) * 4.0f - 0.5f;
    float acc0 = 0.f, acc1 = 0.f, acc2 = 0.f;

#pragma unroll
    for (int k = 0; k < K2; ++k) {
        float py = cy + (float)(k / 3) + vv[k] * ou;
        float px = cx + (float)(k % 3) + hh[k] * ou;

        float y0f = floorf(py), x0f = floorf(px);
        float bb = py - y0f;
        float aa = px - x0f;

        int y0 = min(max((int)y0f, 0), HP - 1);
        int x0 = min(max((int)x0f, 0), WP - 1);
        int y1 = min(y0 + 1, HP - 1);
        int x1 = min(x0 + 1, WP - 1);

        float v00x, v00y, v00z, v01x, v01y, v01z;
        float v10x, v10y, v10z, v11x, v11y, v11z;

        bool inw = (y0 >= Y0) & (y1 <= Y0 + WINH - 1) &
                   (x0 >= X0) & (x1 <= X0 + WINW - 1);
        if (__builtin_expect(inw, 1)) {
            int i00 = (y0 - Y0) * WINW + (x0 - X0);
            int i10 = i00 + (y1 - y0) * WINW;
            bool dx = (x1 > x0);         // false only at clamped far edge
            // adjacent-pair LDS reads -> ds_read2_b64 / ds_read2_b32
            float2 a00 = lA[i00], a01 = lA[i00 + 1];
            float2 a10 = lA[i10], a11 = lA[i10 + 1];
            float  b00 = lB[i00], b01 = lB[i00 + 1];
            float  b10 = lB[i10], b11 = lB[i10 + 1];
            float2 s01 = dx ? a01 : a00;
            float2 s11 = dx ? a11 : a10;
            float  c01 = dx ? b01 : b00;
            float  c11 = dx ? b11 : b10;
            v00x = a00.x; v00y = a00.y; v00z = b00;
            v01x = s01.x; v01y = s01.y; v01z = c01;
            v10x = a10.x; v10y = a10.y; v10z = b10;
            v11x = s11.x; v11y = s11.y; v11z = c11;
        } else {
            // Rare (|offset| beyond halo): exact replay of the verified
            // global reflect path (bit-identical result).
            int sy0 = reflect_src(y0, H), sy1 = reflect_src(y1, H);
            int sx0 = reflect_src(x0, W), sx1 = reflect_src(x1, W);
            size_t i0 = (size_t)sy0 * W + sx0, i1 = (size_t)sy0 * W + sx1;
            size_t i2 = (size_t)sy1 * W + sx0, i3 = (size_t)sy1 * W + sx1;
            v00x = p0[i0]; v01x = p0[i1]; v10x = p0[i2]; v11x = p0[i3];
            v00y = p1[i0]; v01y = p1[i1]; v10y = p1[i2]; v11y = p1[i3];
            v00z = p2[i0]; v01z = p2[i1]; v10z = p2[i2]; v11z = p2[i3];
        }

        float tx_, tu_;
        tx_ = v00x + aa * (v01x - v00x);
        tu_ = v10x + aa * (v11x - v10x);
        acc0 += kv[k] * (tx_ + bb * (tu_ - tx_));
        tx_ = v00y + aa * (v01y - v00y);
        tu_ = v10y + aa * (v11y - v10y);
        acc1 += kv[k] * (tx_ + bb * (tu_ - tx_));
        tx_ = v00z + aa * (v01z - v00z);
        tu_ = v10z + aa * (v11z - v10z);
        acc2 += kv[k] * (tx_ + bb * (tu_ - tx_));
    }

    size_t obase = ((size_t)b * C) * (size_t)HOWO + (size_t)h * WO + w;
    out[obase] = acc0;
    out[obase + (size_t)HOWO] = acc1;
    out[obase + (size_t)(2 * HOWO)] = acc2;
}
} // namespace

extern "C" void kernel_launch(void* const* d_in, const int* in_sizes, int n_in,
                              void* d_out, int out_size, void* d_ws, size_t ws_size,
                              hipStream_t stream) {
    const float* img  = (const float*)d_in[0];
    const float* kern = (const float*)d_in[1];
    const float* offh = (const float*)d_in[2];
    const float* offv = (const float*)d_in[3];
    const float* ou   = (const float*)d_in[4];
    float* out = (float*)d_out;

    // Opt-in to >64 KiB dynamic LDS (host-side attr, graph-capture safe).
    static bool attr_set = false;
    if (!attr_set) {
        hipFuncSetAttribute(reinterpret_cast<const void*>(&ds_fused),
                            hipFuncAttributeMaxDynamicSharedMemorySize,
                            (int)LDS_BYTES);
        attr_set = true;
    }

    hipLaunchKernelGGL(ds_fused, dim3(B * NT), dim3(512), LDS_BYTES, stream,
                       img, kern, offh, offv, ou, out);
}

// Round 4
// 209.490 us; speedup vs baseline: 1.3267x; 1.0583x over previous
//
#include <hip/hip_runtime.h>
#include <cstdint>

namespace {
constexpr int B = 8, C = 3, H = 1024, W = 1024;
constexpr int HO = 256, WO = 256, K2 = 9;
constexpr int HP = H + 2, WP = W + 2;
constexpr int HW = H * W, HOWO = HO * WO;

// One block = one 32x16 output tile, all 3 channels.
constexpr int TW = 32, TH = 16;
constexpr int NTX = WO / TW;            // 8 tiles in x
constexpr int NTY = HO / TH;            // 16
constexpr int NT  = NTX * NTY;          // 128 tiles per image
constexpr int OF = 12;                  // halo px = 3 sigma of 4*N(0,1)
constexpr int WINW = 4 * TW + 2 * OF;   // 152 (x-chunks 16B-aligned: X0-1 = 4w0-12)
constexpr int WINH = 4 * TH + 2 * OF;   // 88
constexpr int WPX  = WINW * WINH;       // 13376 px per plane
constexpr int CPR  = WINW / 4;          // 38 float4-chunks per row
constexpr int CHPP = CPR * WINH;        // 3344 chunks per plane
constexpr size_t LDS_BYTES = (size_t)WPX * 12;  // 160512 <= 163840

__device__ __forceinline__ int reflect_src(int p, int n) {
    // padded index p in [0, n+1] -> source index in [0, n-1] (numpy 'reflect')
    int s = p - 1;
    s = (s < 0) ? -s : s;
    s = (s >= n) ? (2 * n - 2 - s) : s;
    return s;
}

// Async global->LDS DMA, 16B per lane. LDS dest = wave-uniform base + lane*16
// (we pass the wave-uniform base explicitly); global src is PER-LANE.
__device__ __forceinline__ void dma16(const float* g, float* l) {
    __builtin_amdgcn_global_load_lds(
        (const __attribute__((address_space(1))) unsigned int*)g,
        (__attribute__((address_space(3))) unsigned int*)l,
        16, 0, 0);
}

__global__ __launch_bounds__(512) void ds_dma(
    const float* __restrict__ img,
    const float* __restrict__ kern,
    const float* __restrict__ offh,
    const float* __restrict__ offv,
    const float* __restrict__ ou_p,
    float* __restrict__ out) {
    extern __shared__ __align__(16) float smem[];
    float* __restrict__ win0 = smem;              // planar row-major windows
    float* __restrict__ win1 = smem + WPX;        // (linear layout required by
    float* __restrict__ win2 = smem + 2 * WPX;    //  global_load_lds)

    const int b   = blockIdx.x & 7;      // XCD swizzle: image b -> XCD b
    const int t   = blockIdx.x >> 3;     // tile 0..127
    const int tid = threadIdx.x;
    const int w0  = (t & (NTX - 1)) * TW;
    const int h0  = (t >> 3) * TH;
    const int X0  = 4 * w0 - (OF - 1);   // window origin, padded coords
    const int Y0  = 4 * h0 - (OF - 1);

    const float* __restrict__ p0 = img + (size_t)b * (C * HW);
    const float* __restrict__ p1 = p0 + HW;
    const float* __restrict__ p2 = p1 + HW;

    // ---- coef prefetch: 27 independent VGPR loads, issued before the DMA
    // burst; latency hides under staging, drained by the same barrier.
    const int lw = tid & (TW - 1);
    const int lh = tid >> 5;
    const int h = h0 + lh, w = w0 + lw;
    const int pb = (b * K2) * HOWO + h * WO + w;
    float kv[K2], vv[K2], hh[K2];
#pragma unroll
    for (int k = 0; k < K2; ++k) {
        kv[k] = kern[pb + k * HOWO];
        vv[k] = offv[pb + k * HOWO];
        hh[k] = offh[pb + k * HOWO];
    }
    const float ou = ou_p[0];

    // ---- DMA staging: chunk i covers window floats [4i, 4i+4).
    // Per-lane global address handles y-reflect for free (row index only).
    // No intermediate waits: ~20 DMAs/wave in flight, one drain at barrier.
    for (int i = tid; i < CHPP; i += 512) {
        int yy = i / CPR;                 // magic-mul
        int xc = i - yy * CPR;
        int Yp = min(max(Y0 + yy, 0), HP - 1);
        int sy = reflect_src(Yp, H);
        int gx = X0 - 1 + 4 * xc;         // 4-aligned -> 16B-aligned
        gx = min(max(gx, 0), W - 4);      // edge chunks: safe addr, fixed below
        const size_t si = (size_t)sy * W + gx;
        const int lbase = (i & ~63) * 4;  // wave-uniform float offset (i = base+lane)
        dma16(p0 + si, win0 + lbase);
        dma16(p1 + si, win1 + lbase);
        dma16(p2 + si, win2 + lbase);
    }
    __syncthreads();                      // single vmcnt(0) drain, all DMA landed

    // ---- x-edge fixup (only tiles at w0==0 or w0==224): 12 boundary columns
    // were DMA'd from a clamped address; overwrite with exact reflect values.
    const bool ledge = (X0 - 1 < 0);
    const bool redge = (X0 - 1 + 4 * (CPR - 1) > W - 4);
    if (ledge | redge) {                  // block-uniform branch
        const int xbase = ledge ? 0 : (WINW - 12);
        for (int i = tid; i < 12 * WINH; i += 512) {
            int r = i / 12, cc = i - r * 12;
            int xx = xbase + cc;
            int Yp = min(max(Y0 + r, 0), HP - 1);
            int sy = reflect_src(Yp, H);
            int Xp = min(max(X0 + xx, 0), WP - 1);
            int sx = reflect_src(Xp, W);
            size_t si = (size_t)sy * W + sx;
            int wi = r * WINW + xx;
            win0[wi] = p0[si];
            win1[wi] = p1[si];
            win2[wi] = p2[si];
        }
        __syncthreads();
    }

    const float cy = (h + 0.5f) * 4.0f - 0.5f;
    const float cx = (w + 0.5f) * 4.0f - 0.5f;
    float acc0 = 0.f, acc1 = 0.f, acc2 = 0.f;

#pragma unroll
    for (int k = 0; k < K2; ++k) {
        float py = cy + (float)(k / 3) + vv[k] * ou;
        float px = cx + (float)(k % 3) + hh[k] * ou;

        float y0f = floorf(py), x0f = floorf(px);
        float bb = py - y0f;
        float aa = px - x0f;

        int y0 = min(max((int)y0f, 0), HP - 1);
        int x0 = min(max((int)x0f, 0), WP - 1);
        int y1 = min(y0 + 1, HP - 1);
        int x1 = min(x0 + 1, WP - 1);

        float v00x, v00y, v00z, v01x, v01y, v01z;
        float v10x, v10y, v10z, v11x, v11y, v11z;

        bool inw = (y0 >= Y0) & (y1 <= Y0 + WINH - 1) &
                   (x0 >= X0) & (x1 <= X0 + WINW - 1);
        if (__builtin_expect(inw, 1)) {
            int i00 = (y0 - Y0) * WINW + (x0 - X0);
            int i10 = i00 + (y1 - y0) * WINW;
            bool dx = (x1 > x0);          // false only at clamped far edge
            // adjacent-pair reads -> ds_read2_b32 per plane per row
            float a00 = win0[i00], a01 = win0[i00 + 1];
            float a10 = win0[i10], a11 = win0[i10 + 1];
            float b00 = win1[i00], b01 = win1[i00 + 1];
            float b10 = win1[i10], b11 = win1[i10 + 1];
            float c00 = win2[i00], c01 = win2[i00 + 1];
            float c10 = win2[i10], c11 = win2[i10 + 1];
            v00x = a00; v01x = dx ? a01 : a00;
            v10x = a10; v11x = dx ? a11 : a10;
            v00y = b00; v01y = dx ? b01 : b00;
            v10y = b10; v11y = dx ? b11 : b10;
            v00z = c00; v01z = dx ? c01 : c00;
            v10z = c10; v11z = dx ? c11 : c10;
        } else {
            // Rare (|offset| beyond halo): exact replay of the verified
            // global reflect path (bit-identical result).
            int sy0 = reflect_src(y0, H), sy1 = reflect_src(y1, H);
            int sx0 = reflect_src(x0, W), sx1 = reflect_src(x1, W);
            size_t i0 = (size_t)sy0 * W + sx0, i1 = (size_t)sy0 * W + sx1;
            size_t i2 = (size_t)sy1 * W + sx0, i3 = (size_t)sy1 * W + sx1;
            v00x = p0[i0]; v01x = p0[i1]; v10x = p0[i2]; v11x = p0[i3];
            v00y = p1[i0]; v01y = p1[i1]; v10y = p1[i2]; v11y = p1[i3];
            v00z = p2[i0]; v01z = p2[i1]; v10z = p2[i2]; v11z = p2[i3];
        }

        float tx_, tu_;
        tx_ = v00x + aa * (v01x - v00x);
        tu_ = v10x + aa * (v11x - v10x);
        acc0 += kv[k] * (tx_ + bb * (tu_ - tx_));
        tx_ = v00y + aa * (v01y - v00y);
        tu_ = v10y + aa * (v11y - v10y);
        acc1 += kv[k] * (tx_ + bb * (tu_ - tx_));
        tx_ = v00z + aa * (v01z - v00z);
        tu_ = v10z + aa * (v11z - v10z);
        acc2 += kv[k] * (tx_ + bb * (tu_ - tx_));
    }

    size_t obase = ((size_t)b * C) * (size_t)HOWO + (size_t)h * WO + w;
    out[obase] = acc0;
    out[obase + (size_t)HOWO] = acc1;
    out[obase + (size_t)(2 * HOWO)] = acc2;
}
} // namespace

extern "C" void kernel_launch(void* const* d_in, const int* in_sizes, int n_in,
                              void* d_out, int out_size, void* d_ws, size_t ws_size,
                              hipStream_t stream) {
    const float* img  = (const float*)d_in[0];
    const float* kern = (const float*)d_in[1];
    const float* offh = (const float*)d_in[2];
    const float* offv = (const float*)d_in[3];
    const float* ou   = (const float*)d_in[4];
    float* out = (float*)d_out;

    // Opt-in to >64 KiB dynamic LDS (host-side attr, graph-capture safe).
    static bool attr_set = false;
    if (!attr_set) {
        hipFuncSetAttribute(reinterpret_cast<const void*>(&ds_dma),
                            hipFuncAttributeMaxDynamicSharedMemorySize,
                            (int)LDS_BYTES);
        attr_set = true;
    }

    hipLaunchKernelGGL(ds_dma, dim3(B * NT), dim3(512), LDS_BYTES, stream,
                       img, kern, offh, offv, ou, out);
}

// Round 6
// 209.376 us; speedup vs baseline: 1.3274x; 1.0005x over previous
//
#include <hip/hip_runtime.h>
#include <cstdint>

namespace {
constexpr int B = 8, C = 3, H = 1024, W = 1024;
constexpr int HO = 256, WO = 256, K2 = 9;
constexpr int HP = H + 2, WP = W + 2;
constexpr int HW = H * W, HOWO = HO * WO;

// One block = one 32x16 output tile, all 3 channels.
constexpr int TW = 32, TH = 16;
constexpr int NTX = WO / TW;            // 8 tiles in x
constexpr int NTY = HO / TH;            // 16
constexpr int NT  = NTX * NTY;          // 128 tiles per image
constexpr int OF = 12;                  // halo px = 3.1 sigma of 4*N(0,1)
constexpr int WINW = 4 * TW + 2 * OF;   // 152 (x-chunks 16B-aligned: X0-1 = 4w0-12)
constexpr int WINH = 4 * TH + 2 * OF;   // 88
constexpr int WPX  = WINW * WINH;       // 13376 px per plane
constexpr int CPR  = WINW / 4;          // 38 float4-chunks per row
constexpr int CHPP = CPR * WINH;        // 3344 chunks per plane
constexpr size_t LDS_BYTES = (size_t)WPX * 12 + 16;  // +spare for [i+1] reads

__device__ __forceinline__ int reflect_src(int p, int n) {
    // padded index p in [0, n+1] -> source index in [0, n-1] (numpy 'reflect')
    int s = p - 1;
    s = (s < 0) ? -s : s;
    s = (s >= n) ? (2 * n - 2 - s) : s;
    return s;
}

// Async global->LDS DMA, 16B per lane. LDS dest = wave-uniform base + lane*16;
// global src is per-lane (y-reflect folds into the address for free).
__device__ __forceinline__ void dma16(const float* g, float* l) {
    __builtin_amdgcn_global_load_lds(
        (const __attribute__((address_space(1))) unsigned int*)g,
        (__attribute__((address_space(3))) unsigned int*)l,
        16, 0, 0);
}

__global__ __launch_bounds__(512, 2) void ds_batch(
    const float* __restrict__ img,
    const float* __restrict__ kern,
    const float* __restrict__ offh,
    const float* __restrict__ offv,
    const float* __restrict__ ou_p,
    float* __restrict__ out) {
    extern __shared__ __align__(16) float smem[];
    float* __restrict__ win0 = smem;              // planar row-major windows
    float* __restrict__ win1 = smem + WPX;        // (linear layout required by
    float* __restrict__ win2 = smem + 2 * WPX;    //  global_load_lds)

    const int b   = blockIdx.x & 7;      // XCD swizzle: image b -> XCD b
    const int t   = blockIdx.x >> 3;     // tile 0..127
    const int tid = threadIdx.x;
    const int w0  = (t & (NTX - 1)) * TW;
    const int h0  = (t >> 3) * TH;
    const int X0  = 4 * w0 - (OF - 1);   // window origin, padded coords
    const int Y0  = 4 * h0 - (OF - 1);

    const float* __restrict__ p0 = img + (size_t)b * (C * HW);
    const float* __restrict__ p1 = p0 + HW;
    const float* __restrict__ p2 = p1 + HW;

    // ---- coef prefetch: 27 independent VGPR loads, issued before the DMA
    // burst; compiler can consume them at vmcnt(#DMA) while DMAs fly.
    const int lw = tid & (TW - 1);
    const int lh = tid >> 5;
    const int h = h0 + lh, w = w0 + lw;
    const int pb = (b * K2) * HOWO + h * WO + w;
    float kv[K2], vv[K2], hh[K2];
#pragma unroll
    for (int k = 0; k < K2; ++k) {
        kv[k] = kern[pb + k * HOWO];
        vv[k] = offv[pb + k * HOWO];
        hh[k] = offh[pb + k * HOWO];
    }
    const float ou = ou_p[0];

    // ---- DMA staging: chunk i covers window floats [4i, 4i+4). No
    // intermediate waits; one vmcnt(0) drain at the barrier.
    for (int i = tid; i < CHPP; i += 512) {
        int yy = i / CPR;
        int xc = i - yy * CPR;
        int Yp = min(max(Y0 + yy, 0), HP - 1);
        int sy = reflect_src(Yp, H);
        int gx = X0 - 1 + 4 * xc;         // 4-aligned -> 16B-aligned
        gx = min(max(gx, 0), W - 4);      // edge chunks: safe addr, fixed below
        const size_t si = (size_t)sy * W + gx;
        const int lbase = (i & ~63) * 4;  // wave-uniform float offset
        dma16(p0 + si, win0 + lbase);
        dma16(p1 + si, win1 + lbase);
        dma16(p2 + si, win2 + lbase);
    }

    // ---- pre-barrier coord math for ALL taps: depends only on coefs, so it
    // executes under the DMA-drain window instead of after the barrier.
    const float cy = (h + 0.5f) * 4.0f - 0.5f;
    const float cx = (w + 0.5f) * 4.0f - 0.5f;
    int   i00c[K2], i10c[K2];
    bool  dxs[K2];
    float aav[K2], bbv[K2], kve[K2];
    unsigned oow = 0;                     // 9-bit out-of-window mask
#pragma unroll
    for (int k = 0; k < K2; ++k) {
        float py = cy + (float)(k / 3) + vv[k] * ou;
        float px = cx + (float)(k % 3) + hh[k] * ou;
        float y0f = floorf(py), x0f = floorf(px);
        bbv[k] = py - y0f;
        aav[k] = px - x0f;
        int y0 = min(max((int)y0f, 0), HP - 1);
        int x0 = min(max((int)x0f, 0), WP - 1);
        int y1 = min(y0 + 1, HP - 1);
        int x1 = min(x0 + 1, WP - 1);
        bool inw = (y0 >= Y0) & (y1 <= Y0 + WINH - 1) &
                   (x0 >= X0) & (x1 <= X0 + WINW - 1);
        int i00 = (y0 - Y0) * WINW + (x0 - X0);
        int i10 = i00 + (y1 - y0) * WINW;
        i00c[k] = inw ? i00 : 0;          // canonical safe slot for oow lanes
        i10c[k] = inw ? i10 : 0;
        dxs[k]  = inw & (x1 > x0);
        kve[k]  = inw ? kv[k] : 0.f;      // oow contribution added in fixup
        oow |= (inw ? 0u : 1u) << k;
    }
    __syncthreads();                      // drains vmcnt(0): all DMA landed

    // ---- x-edge fixup (tiles at w0==0 or w0==224 only): boundary columns
    // were DMA'd from a clamped address; overwrite with exact reflect values.
    const bool ledge = (X0 - 1 < 0);
    const bool redge = (X0 - 1 + 4 * (CPR - 1) > W - 4);
    if (ledge | redge) {                  // block-uniform branch
        const int xbase = ledge ? 0 : (WINW - 12);
        for (int i = tid; i < 12 * WINH; i += 512) {
            int r = i / 12, cc = i - r * 12;
            int xx = xbase + cc;
            int Yp = min(max(Y0 + r, 0), HP - 1);
            int sy = reflect_src(Yp, H);
            int Xp = min(max(X0 + xx, 0), WP - 1);
            int sx = reflect_src(Xp, W);
            size_t si = (size_t)sy * W + sx;
            int wi = r * WINW + xx;
            win0[wi] = p0[si];
            win1[wi] = p1[si];
            win2[wi] = p2[si];
        }
        __syncthreads();
    }

    // ---- batched gather: 108 unconditional scalar LDS reads (54 ds_read2),
    // no branches between them -> single deep LDS queue, throughput-bound.
    float a00[K2], a01[K2], a10[K2], a11[K2];
    float b00[K2], b01[K2], b10[K2], b11[K2];
    float c00[K2], c01[K2], c10[K2], c11[K2];
#pragma unroll
    for (int k = 0; k < K2; ++k) {
        int i0 = i00c[k], i1 = i10c[k];
        a00[k] = win0[i0]; a01[k] = win0[i0 + 1];
        a10[k] = win0[i1]; a11[k] = win0[i1 + 1];
        b00[k] = win1[i0]; b01[k] = win1[i0 + 1];
        b10[k] = win1[i1]; b11[k] = win1[i1 + 1];
        c00[k] = win2[i0]; c01[k] = win2[i0 + 1];
        c10[k] = win2[i1]; c11[k] = win2[i1 + 1];
    }

    float acc0 = 0.f, acc1 = 0.f, acc2 = 0.f;
#pragma unroll
    for (int k = 0; k < K2; ++k) {
        float aa = aav[k], bb = bbv[k], kw = kve[k];
        float s01 = dxs[k] ? a01[k] : a00[k];
        float s11 = dxs[k] ? a11[k] : a10[k];
        float t01 = dxs[k] ? b01[k] : b00[k];
        float t11 = dxs[k] ? b11[k] : b10[k];
        float u01 = dxs[k] ? c01[k] : c00[k];
        float u11 = dxs[k] ? c11[k] : c10[k];
        float tx_, tu_;
        tx_ = a00[k] + aa * (s01 - a00[k]);
        tu_ = a10[k] + aa * (s11 - a10[k]);
        acc0 += kw * (tx_ + bb * (tu_ - tx_));
        tx_ = b00[k] + aa * (t01 - b00[k]);
        tu_ = b10[k] + aa * (t11 - b10[k]);
        acc1 += kw * (tx_ + bb * (tu_ - tx_));
        tx_ = c00[k] + aa * (u01 - c00[k]);
        tu_ = c10[k] + aa * (u11 - c10[k]);
        acc2 += kw * (tx_ + bb * (tu_ - tx_));
    }

    // ---- deferred fixup for the rare out-of-halo taps (~3e-4 of taps):
    // exact replay of the verified global reflect path.
    if (__builtin_expect(__any(oow != 0), 0)) {
#pragma unroll
        for (int k = 0; k < K2; ++k) {
            bool bad = (oow >> k) & 1u;
            if (__any(bad)) {
                if (bad) {
                    float py = cy + (float)(k / 3) + vv[k] * ou;
                    float px = cx + (float)(k % 3) + hh[k] * ou;
                    float y0f = floorf(py), x0f = floorf(px);
                    float bb = py - y0f, aa = px - x0f;
                    int y0 = min(max((int)y0f, 0), HP - 1);
                    int x0 = min(max((int)x0f, 0), WP - 1);
                    int y1 = min(y0 + 1, HP - 1);
                    int x1 = min(x0 + 1, WP - 1);
                    int sy0 = reflect_src(y0, H), sy1 = reflect_src(y1, H);
                    int sx0 = reflect_src(x0, W), sx1 = reflect_src(x1, W);
                    size_t j0 = (size_t)sy0 * W + sx0, j1 = (size_t)sy0 * W + sx1;
                    size_t j2 = (size_t)sy1 * W + sx0, j3 = (size_t)sy1 * W + sx1;
                    float tx_, tu_;
                    tx_ = p0[j0] + aa * (p0[j1] - p0[j0]);
                    tu_ = p0[j2] + aa * (p0[j3] - p0[j2]);
                    acc0 += kv[k] * (tx_ + bb * (tu_ - tx_));
                    tx_ = p1[j0] + aa * (p1[j1] - p1[j0]);
                    tu_ = p1[j2] + aa * (p1[j3] - p1[j2]);
                    acc1 += kv[k] * (tx_ + bb * (tu_ - tx_));
                    tx_ = p2[j0] + aa * (p2[j1] - p2[j0]);
                    tu_ = p2[j2] + aa * (p2[j3] - p2[j2]);
                    acc2 += kv[k] * (tx_ + bb * (tu_ - tx_));
                }
            }
        }
    }

    size_t obase = ((size_t)b * C) * (size_t)HOWO + (size_t)h * WO + w;
    out[obase] = acc0;
    out[obase + (size_t)HOWO] = acc1;
    out[obase + (size_t)(2 * HOWO)] = acc2;
}
} // namespace

extern "C" void kernel_launch(void* const* d_in, const int* in_sizes, int n_in,
                              void* d_out, int out_size, void* d_ws, size_t ws_size,
                              hipStream_t stream) {
    const float* img  = (const float*)d_in[0];
    const float* kern = (const float*)d_in[1];
    const float* offh = (const float*)d_in[2];
    const float* offv = (const float*)d_in[3];
    const float* ou   = (const float*)d_in[4];
    float* out = (float*)d_out;

    // Opt-in to >64 KiB dynamic LDS (host-side attr, graph-capture safe).
    static bool attr_set = false;
    if (!attr_set) {
        hipFuncSetAttribute(reinterpret_cast<const void*>(&ds_batch),
                            hipFuncAttributeMaxDynamicSharedMemorySize,
                            (int)LDS_BYTES);
        attr_set = true;
    }

    hipLaunchKernelGGL(ds_batch, dim3(B * NT), dim3(512), LDS_BYTES, stream,
                       img, kern, offh, offv, ou, out);
}

// Round 7
// 199.707 us; speedup vs baseline: 1.3917x; 1.0484x over previous
//
#include <hip/hip_runtime.h>
#include <cstdint>

namespace {
constexpr int B = 8, C = 3, H = 1024, W = 1024;
constexpr int HO = 256, WO = 256, K2 = 9;
constexpr int HP = H + 2, WP = W + 2;
constexpr int HW = H * W, HOWO = HO * WO;

constexpr int TW = 32, TH = 16;         // 512 outputs per tile, 1/thread
constexpr int NTX = WO / TW;            // 8
constexpr int OF = 12;                  // halo = 3 sigma of 4*N(0,1)
constexpr int WINW = 4 * TW + 2 * OF;   // 152
constexpr int WINH = 4 * TH + 2 * OF;   // 88
constexpr int WPX  = WINW * WINH;       // 13376 floats per plane window
constexpr int CPR  = WINW / 4;          // 38 16B-chunks per row
constexpr int NCHUNK = CPR * WINH;      // 3344 chunks per plane
constexpr int NCPAD  = 3584;            // 7*512 (static trip count + pad)
constexpr int BUF_FLTS = NCPAD * 4;     // 14336 floats per buffer
constexpr size_t LDS_BYTES = (size_t)BUF_FLTS * 2 * 4;  // 114688 B

__device__ __forceinline__ int reflect_src(int p, int n) {
    // padded index p in [0, n+1] -> source index in [0, n-1] (numpy 'reflect')
    int s = p - 1;
    s = (s < 0) ? -s : s;
    s = (s >= n) ? (2 * n - 2 - s) : s;
    return s;
}

__device__ __forceinline__ void dma16(const float* g, float* l) {
    __builtin_amdgcn_global_load_lds(
        (const __attribute__((address_space(1))) unsigned int*)g,
        (__attribute__((address_space(3))) unsigned int*)l,
        16, 0, 0);
}

// Persistent pipeline: 1 block/CU, 4 tiles/block, 12 plane-steps.
// Step s: [issue DMAs for plane s+1 into buf.alt] [gather plane s from
// buf.cur] [sync = vmcnt(0) drain AFTER the gather ran] [swap].
__global__ __launch_bounds__(512) void ds_pipe(
    const float* __restrict__ img,
    const float* __restrict__ kern,
    const float* __restrict__ offh,
    const float* __restrict__ offv,
    const float* __restrict__ ou_p,
    float* __restrict__ out) {
    extern __shared__ __align__(16) float smem[];
    float* cur = smem;
    float* nxt = smem + BUF_FLTS;

    const int b    = blockIdx.x & 7;     // XCD swizzle: image b -> XCD b
    const int slot = blockIdx.x >> 3;    // 0..31: 4 x-adjacent tiles each
    const int tid  = threadIdx.x;
    const int t0   = slot * 4;

    const float* __restrict__ p0 = img + (size_t)b * (C * HW);
    const float* __restrict__ p1 = p0 + HW;
    const float* __restrict__ p2 = p1 + HW;
    const float ou = ou_p[0];

    // Issue one plane's window DMAs (7 per wave, fire-and-forget).
    auto stage = [&](int t, const float* pc, float* buf) {
        const int w0 = (t & (NTX - 1)) * TW, h0 = (t >> 3) * TH;
        const int X0 = 4 * w0 - (OF - 1), Y0 = 4 * h0 - (OF - 1);
#pragma unroll
        for (int it = 0; it < 7; ++it) {
            if ((tid & ~63) + it * 512 < NCHUNK) {   // wave-uniform skip
                int i = tid + it * 512;
                int isrc = min(i, NCHUNK - 1);
                int yy = isrc / CPR;
                int xc = isrc - yy * CPR;
                int Yp = min(max(Y0 + yy, 0), HP - 1);
                int sy = reflect_src(Yp, H);          // y-reflect exact in addr
                int gx = min(max(X0 - 1 + 4 * xc, 0), W - 4);
                dma16(pc + (size_t)sy * W + gx, buf + (i & ~63) * 4);
            }
        }
    };

    // Only padded x==0 / x==WP-1 are wrong under the linear DMA rule; fix
    // that single column (cross-wave LDS write -> caller adds a sync).
    auto edgefix = [&](int t, const float* pc, float* buf) -> bool {
        const int w0 = (t & (NTX - 1)) * TW;
        const bool ledge = (w0 == 0), redge = (w0 == WO - TW);
        if (!(ledge | redge)) return false;
        const int h0 = (t >> 3) * TH, Y0 = 4 * h0 - (OF - 1);
        const int X0 = 4 * w0 - (OF - 1);
        const int sfix = ledge ? (OF - 1) : ((WP - 1) - X0);  // 11 / 140
        const int xsrc = ledge ? 1 : (W - 2);                 // reflect value
        if (tid < WINH) {
            int Yp = min(max(Y0 + tid, 0), HP - 1);
            int sy = reflect_src(Yp, H);
            buf[tid * WINW + sfix] = pc[(size_t)sy * W + xsrc];
        }
        return true;
    };

    // ---- per-tile state (constant-indexed in unrolled loops -> registers)
    float kvr[K2], vvr[K2], hhr[K2], aav[K2], bbv[K2];
    int   i00c[K2], i10c[K2];
    unsigned oowm = 0, dxm = 0;
    float cyf = 0.f, cxf = 0.f;
    int hq = 0, wq = 0;

    // Gather one channel's 9 taps from cur + exact global replay for rare
    // out-of-halo taps.
    auto gacc = [&](const float* pc) -> float {
        float acc = 0.f;
#pragma unroll
        for (int k = 0; k < K2; ++k) {
            int i0 = i00c[k], i1 = i10c[k];
            float a00 = cur[i0], a01 = cur[i0 + 1];
            float a10 = cur[i1], a11 = cur[i1 + 1];
            bool dx = (dxm >> k) & 1u;
            float s01 = dx ? a01 : a00;
            float s11 = dx ? a11 : a10;
            float kw = ((oowm >> k) & 1u) ? 0.f : kvr[k];
            float tx = a00 + aav[k] * (s01 - a00);
            float tu = a10 + aav[k] * (s11 - a10);
            acc += kw * (tx + bbv[k] * (tu - tx));
        }
        if (__builtin_expect(__any(oowm != 0), 0)) {
#pragma unroll
            for (int k = 0; k < K2; ++k) {
                bool bad = (oowm >> k) & 1u;
                if (__any(bad)) {
                    if (bad) {
                        float py = cyf + (float)(k / 3) + vvr[k] * ou;
                        float px = cxf + (float)(k % 3) + hhr[k] * ou;
                        float y0f = floorf(py), x0f = floorf(px);
                        float bb = py - y0f, aa = px - x0f;
                        int y0 = min(max((int)y0f, 0), HP - 1);
                        int x0 = min(max((int)x0f, 0), WP - 1);
                        int y1 = min(y0 + 1, HP - 1);
                        int x1 = min(x0 + 1, WP - 1);
                        int sy0 = reflect_src(y0, H), sy1 = reflect_src(y1, H);
                        int sx0 = reflect_src(x0, W), sx1 = reflect_src(x1, W);
                        size_t j0 = (size_t)sy0 * W + sx0, j1 = (size_t)sy0 * W + sx1;
                        size_t j2 = (size_t)sy1 * W + sx0, j3 = (size_t)sy1 * W + sx1;
                        float tx = pc[j0] + aa * (pc[j1] - pc[j0]);
                        float tu = pc[j2] + aa * (pc[j3] - pc[j2]);
                        acc += kvr[k] * (tx + bb * (tu - tx));
                    }
                }
            }
        }
        return acc;
    };

    // ---- prologue: coefs(tile0) + plane(t0,c0); one exposed drain.
    float kn[K2], vn[K2], hn[K2];
    {
        const int w0 = (t0 & (NTX - 1)) * TW, h0 = (t0 >> 3) * TH;
        const int pb = (b * K2) * HOWO + (h0 + (tid >> 5)) * WO + (w0 + (tid & 31));
#pragma unroll
        for (int k = 0; k < K2; ++k) {
            kn[k] = kern[pb + k * HOWO];
            vn[k] = offv[pb + k * HOWO];
            hn[k] = offh[pb + k * HOWO];
        }
    }
    stage(t0, p0, cur);
    __syncthreads();

    for (int j = 0; j < 4; ++j) {
        const int t  = t0 + j;
        const int w0 = (t & (NTX - 1)) * TW, h0 = (t >> 3) * TH;
        const int X0 = 4 * w0 - (OF - 1), Y0 = 4 * h0 - (OF - 1);
        hq = h0 + (tid >> 5);
        wq = w0 + (tid & 31);
        cyf = (hq + 0.5f) * 4.0f - 0.5f;
        cxf = (wq + 0.5f) * 4.0f - 0.5f;

        // ===== step c0 (cur = plane(t,0)) =====
        stage(t, p1, nxt);                     // prefetch c1
        oowm = 0; dxm = 0;
#pragma unroll
        for (int k = 0; k < K2; ++k) {         // coord math, once per tile
            kvr[k] = kn[k]; vvr[k] = vn[k]; hhr[k] = hn[k];
            float py = cyf + (float)(k / 3) + vvr[k] * ou;
            float px = cxf + (float)(k % 3) + hhr[k] * ou;
            float y0f = floorf(py), x0f = floorf(px);
            bbv[k] = py - y0f; aav[k] = px - x0f;
            int y0 = min(max((int)y0f, 0), HP - 1);
            int x0 = min(max((int)x0f, 0), WP - 1);
            int y1 = min(y0 + 1, HP - 1);
            int x1 = min(x0 + 1, WP - 1);
            bool inw = (y0 >= Y0) & (y1 <= Y0 + WINH - 1) &
                       (x0 >= X0) & (x1 <= X0 + WINW - 1);
            int i00 = (y0 - Y0) * WINW + (x0 - X0);
            int i10 = i00 + (y1 - y0) * WINW;
            i00c[k] = inw ? i00 : 0;
            i10c[k] = inw ? i10 : 0;
            dxm  |= (unsigned)(inw & (x1 > x0)) << k;
            oowm |= (inw ? 0u : 1u) << k;
        }
        if (edgefix(t, p0, cur)) __syncthreads();
        float acc0 = gacc(p0);
        __syncthreads();
        { float* tmp = cur; cur = nxt; nxt = tmp; }

        // ===== step c1 =====
        stage(t, p2, nxt);                     // prefetch c2
        if (edgefix(t, p1, cur)) __syncthreads();
        float acc1 = gacc(p1);
        __syncthreads();
        { float* tmp = cur; cur = nxt; nxt = tmp; }

        // ===== step c2 =====
        if (j < 3) {                           // prefetch next tile c0 + coefs
            stage(t + 1, p0, nxt);
            const int tn = t + 1;
            const int w0n = (tn & (NTX - 1)) * TW, h0n = (tn >> 3) * TH;
            const int pbn = (b * K2) * HOWO +
                            (h0n + (tid >> 5)) * WO + (w0n + (tid & 31));
#pragma unroll
            for (int k = 0; k < K2; ++k) {
                kn[k] = kern[pbn + k * HOWO];
                vn[k] = offv[pbn + k * HOWO];
                hn[k] = offh[pbn + k * HOWO];
            }
        }
        if (edgefix(t, p2, cur)) __syncthreads();
        float acc2 = gacc(p2);

        size_t obase = ((size_t)b * C) * (size_t)HOWO + (size_t)hq * WO + wq;
        out[obase] = acc0;
        out[obase + (size_t)HOWO] = acc1;
        out[obase + (size_t)(2 * HOWO)] = acc2;

        if (j < 3) {
            __syncthreads();
            { float* tmp = cur; cur = nxt; nxt = tmp; }
        }
    }
}
} // namespace

extern "C" void kernel_launch(void* const* d_in, const int* in_sizes, int n_in,
                              void* d_out, int out_size, void* d_ws, size_t ws_size,
                              hipStream_t stream) {
    const float* img  = (const float*)d_in[0];
    const float* kern = (const float*)d_in[1];
    const float* offh = (const float*)d_in[2];
    const float* offv = (const float*)d_in[3];
    const float* ou   = (const float*)d_in[4];
    float* out = (float*)d_out;

    // Opt-in to >64 KiB dynamic LDS (host-side attr, graph-capture safe).
    static bool attr_set = false;
    if (!attr_set) {
        hipFuncSetAttribute(reinterpret_cast<const void*>(&ds_pipe),
                            hipFuncAttributeMaxDynamicSharedMemorySize,
                            (int)LDS_BYTES);
        attr_set = true;
    }

    hipLaunchKernelGGL(ds_pipe, dim3(B * 32), dim3(512), LDS_BYTES, stream,
                       img, kern, offh, offv, ou, out);
}